// Round 7
// baseline (258.077 us; speedup 1.0000x reference)
//
#include <hip/hip_runtime.h>
#include <math.h>

#define N_NODES 3000
#define T_STEPS 12
#define F_INP 2
#define HEADS 8
#define HID 32
#define E_EDGES 32000
#define E_TOT (E_EDGES + N_NODES)   // 35000 with self-loops
#define NEG_SLOPE 0.2f
#define OUT_F 24                    // F_OUT * T_OUT
#define CHUNKS 8                    // 8 slots x 8 chunks = 64 edges in regs
#define NT (N_NODES * T_STEPS)      // 36000

__device__ __forceinline__ float sigm(float x) {
    return 1.0f / (1.0f + __expf(-x));
}
__device__ __forceinline__ float tanh_f(float x) {
    return 1.0f - 2.0f / (__expf(2.0f * x) + 1.0f);
}
// broadcast lane l's value via scalar pipe (v_readlane). CONVERGENT: call at
// full exec only (round-4 post-mortem).
__device__ __forceinline__ float rdlane(float v, int l) {
    return __int_as_float(__builtin_amdgcn_readlane(__float_as_int(v), l));
}

// ---------------------------------------------------------------------------
// k_init: blocks 0..11 zero deg; block 12 computes proj; blocks 13.. build
// Xt[t][n] = (x0,x1) so k_gat's per-edge gathers hit a 24 KB L1-resident
// plane per t instead of scattering over the full 288 KB X.
// proj[w*8+h]: w=0 <gw_f0,att_src>, 1 <gw_f1,att_src>, 2 <gw_f0,att_dst>, 3 <gw_f1,att_dst>
// ---------------------------------------------------------------------------
__global__ void k_init(int* __restrict__ deg,
                       const float* __restrict__ gat_w,
                       const float* __restrict__ att_src,
                       const float* __restrict__ att_dst,
                       float* __restrict__ proj,
                       const float* __restrict__ X,
                       float2* __restrict__ Xt) {
    int b = blockIdx.x;
    if (b < 12) {
        int i = b * 256 + threadIdx.x;
        if (i < N_NODES) deg[i] = 0;
    } else if (b == 12) {
        int tid = threadIdx.x;
        if (tid < 32) {
            int h = tid & 7, w = tid >> 3;
            const float* att = (w < 2) ? att_src : att_dst;
            int f = w & 1;
            float s = 0.0f;
            for (int c = 0; c < 32; c++)
                s += gat_w[((h * 32 + c) * 2) + f] * att[h * 32 + c];
            proj[w * 8 + h] = s;
        }
    } else {
        int i = (b - 13) * 256 + threadIdx.x;   // i = n*T + t
        if (i < NT) {
            int n = i / T_STEPS, t = i - n * T_STEPS;
            float2 v = *(const float2*)&X[(size_t)i * 2];
            Xt[(size_t)t * N_NODES + n] = v;
        }
    }
}

__global__ void k_deg(const int* __restrict__ ei, int* __restrict__ deg) {
    int i = blockIdx.x * blockDim.x + threadIdx.x;
    if (i >= E_TOT) return;
    int d = (i < E_EDGES) ? ei[E_EDGES + i] : (i - E_EDGES);
    atomicAdd(&deg[d], 1);
}

__global__ __launch_bounds__(256) void k_scan(const int* __restrict__ deg,
                                              int* __restrict__ row_start,
                                              int* __restrict__ cursor) {
    __shared__ int part[256];
    int tid = threadIdx.x;
    const int CH = (N_NODES + 255) / 256;   // 12
    int base = tid * CH;
    int s = 0;
    for (int i = 0; i < CH; i++) {
        int idx = base + i;
        if (idx < N_NODES) s += deg[idx];
    }
    part[tid] = s;
    __syncthreads();
    if (tid == 0) {
        int run = 0;
        for (int i = 0; i < 256; i++) { int tmp = part[i]; part[i] = run; run += tmp; }
        row_start[N_NODES] = run;           // == E_TOT
    }
    __syncthreads();
    int off = part[tid];
    for (int i = 0; i < CH; i++) {
        int idx = base + i;
        if (idx < N_NODES) {
            row_start[idx] = off;
            cursor[idx] = off;
            off += deg[idx];
        }
    }
}

__global__ void k_scatter(const int* __restrict__ ei, int* __restrict__ cursor,
                          int* __restrict__ csr_src) {
    int i = blockIdx.x * blockDim.x + threadIdx.x;
    if (i >= E_TOT) return;
    int s, d;
    if (i < E_EDGES) { s = ei[i]; d = ei[E_EDGES + i]; }
    else             { s = i - E_EDGES; d = s; }
    int pos = atomicAdd(&cursor[d], 1);
    csr_src[pos] = s;
}

// ---------------------------------------------------------------------------
// k_gat: one wave64 per (t,n). lanes = 8 heads x 8 slots. Edge values in
// registers, reductions via shfl_xor(1,2,4); head-sum broadcast via
// v_readlane AT FULL EXEC. Reads Xt (L1-resident 24 KB plane per t).
// gat_out layout: [n][t][c]
// ---------------------------------------------------------------------------
__global__ __launch_bounds__(256) void k_gat(const float2* __restrict__ Xt,
                                             const int* __restrict__ row_start,
                                             const int* __restrict__ csr_src,
                                             const float* __restrict__ proj,
                                             const float* __restrict__ gat_w,
                                             const float* __restrict__ gat_b,
                                             float* __restrict__ gat_out) {
    int pair = blockIdx.x * 4 + (threadIdx.x >> 6);   // t*N + n
    int t = pair / N_NODES, n = pair - t * N_NODES;
    int lane = threadIdx.x & 63;
    int h = lane >> 3, slot = lane & 7;
    int rs = row_start[n];
    int deg = row_start[n + 1] - rs;     // >= 1 (self-loop)
    const float2* Xp = Xt + (size_t)t * N_NODES;
    float ps0 = proj[h], ps1 = proj[8 + h];
    float pd0 = proj[16 + h], pd1 = proj[24 + h];
    float2 xd = Xp[n];
    float ad = fmaf(xd.x, pd0, xd.y * pd1);

    float x0c[CHUNKS], x1c[CHUNKS], sc[CHUNKS];
    float m = -1e30f;
    #pragma unroll
    for (int c = 0; c < CHUNKS; c++) {
        if (8 * c < deg) {                       // wave-uniform branch
            int e = slot + 8 * c;
            int idx = rs + (e < deg ? e : deg - 1);
            int src = csr_src[idx];
            float2 xv = Xp[src];
            x0c[c] = xv.x; x1c[c] = xv.y;
            float s = fmaf(xv.x, ps0, fmaf(xv.y, ps1, ad));
            s = (s > 0.0f) ? s : NEG_SLOPE * s;
            sc[c] = (e < deg) ? s : -1e30f;
            m = fmaxf(m, sc[c]);
        } else { x0c[c] = 0.0f; x1c[c] = 0.0f; sc[c] = -1e30f; }
    }
    // deg > 64 fallback (never taken for this graph; wave-uniform)
    for (int e = 64 + slot; e < deg; e += 8) {
        float2 xv = Xp[csr_src[rs + e]];
        float s = fmaf(xv.x, ps0, fmaf(xv.y, ps1, ad));
        s = (s > 0.0f) ? s : NEG_SLOPE * s;
        m = fmaxf(m, s);
    }
    m = fmaxf(m, __shfl_xor(m, 1, 64));
    m = fmaxf(m, __shfl_xor(m, 2, 64));
    m = fmaxf(m, __shfl_xor(m, 4, 64));

    float den = 0.0f, S0 = 0.0f, S1 = 0.0f;
    #pragma unroll
    for (int c = 0; c < CHUNKS; c++) {
        if (8 * c < deg) {
            float a = __expf(sc[c] - m);          // masked slots: exp(-1e30)=0
            den += a;
            S0 = fmaf(a, x0c[c], S0);
            S1 = fmaf(a, x1c[c], S1);
        }
    }
    for (int e = 64 + slot; e < deg; e += 8) {    // fallback recompute
        float2 xv = Xp[csr_src[rs + e]];
        float s = fmaf(xv.x, ps0, fmaf(xv.y, ps1, ad));
        s = (s > 0.0f) ? s : NEG_SLOPE * s;
        float a = __expf(s - m);
        den += a; S0 = fmaf(a, xv.x, S0); S1 = fmaf(a, xv.y, S1);
    }
    #pragma unroll
    for (int mm = 1; mm <= 4; mm <<= 1) {
        den += __shfl_xor(den, mm, 64);
        S0  += __shfl_xor(S0,  mm, 64);
        S1  += __shfl_xor(S1,  mm, 64);
    }
    float inv = 0.125f / den;
    float v0 = S0 * inv, v1 = S1 * inv;

    // per-head broadcasts at FULL EXEC (readlane is convergent; round-4 fix)
    float a0[HEADS], a1[HEADS];
    #pragma unroll
    for (int hh = 0; hh < HEADS; hh++) {
        a0[hh] = rdlane(v0, hh * 8);
        a1[hh] = rdlane(v1, hh * 8);
    }

    // branch-free projection: all lanes compute, lanes 0..31 store
    int cc = lane & 31;
    float acc = gat_b[cc];
    #pragma unroll
    for (int hh = 0; hh < HEADS; hh++) {
        float2 g = *(const float2*)&gat_w[(hh * 32 + cc) * 2];
        acc = fmaf(a0[hh], g.x, fmaf(a1[hh], g.y, acc));
    }
    if (lane < 32)
        gat_out[((size_t)n * T_STEPS + t) * HID + cc] = acc;
}

// ---------------------------------------------------------------------------
// k_proj0: layer-0 input projection gx0[p][r] = b_ih0[r]+b_hh0[r] +
// gat_out[p] . w_ih0[r], p = n*12+t, r = gate row (0..127). Fully parallel
// (4.6M outputs) -> removes ~1150 latency-exposed ops from each k_lstm wave.
// ---------------------------------------------------------------------------
__global__ __launch_bounds__(256) void k_proj0(const float* __restrict__ gat_out,
                                               const float* __restrict__ w_ih0,
                                               const float* __restrict__ b_ih0,
                                               const float* __restrict__ b_hh0,
                                               float* __restrict__ gx0) {
    int p = blockIdx.x * 2 + (threadIdx.x >> 7);
    int r = threadIdx.x & 127;
    const float* x = &gat_out[(size_t)p * HID];
    float acc = b_ih0[r] + b_hh0[r];
    #pragma unroll
    for (int q = 0; q < 8; q++) {
        float4 xv = *(const float4*)&x[4 * q];
        float4 wv = *(const float4*)&w_ih0[r * 32 + 4 * q];
        acc = fmaf(xv.x, wv.x, acc);
        acc = fmaf(xv.y, wv.y, acc);
        acc = fmaf(xv.z, wv.z, acc);
        acc = fmaf(xv.w, wv.w, acc);
    }
    gx0[(size_t)p * 128 + r] = acc;
}

// ---------------------------------------------------------------------------
// k_lstm: fused 2-layer LSTM + FC. One wave64 per node. Split-gate: half 0
// owns (i,f), half 1 owns (g,o); weight columns in VGPRs. h broadcast via
// v_readlane; 4x16 split-k chains halve the serial fma depth.
// __launch_bounds__(64,3): grid supplies only ~3 waves/SIMD, so give the
// compiler 170 VGPRs -- round-6's default (68 VGPR) forced the arrays out
// of registers and serialized the kernel (85 us, VALUBusy 37%).
// ---------------------------------------------------------------------------
__global__ __launch_bounds__(64, 3)
void k_lstm(const float* __restrict__ gx0,     // [n*12+t][128]
            const float* __restrict__ w_hh0,
            const float* __restrict__ w_ih1,
            const float* __restrict__ w_hh1,
            const float* __restrict__ b_ih1,
            const float* __restrict__ b_hh1,
            const float* __restrict__ fc_w,
            const float* __restrict__ fc_b,
            float* __restrict__ out) {         // [n][24]
    int n = blockIdx.x;
    int lane = threadIdx.x;
    int j = lane & 31, half = lane >> 5;
    int rowA = half * 64 + j;        // gate i (half0) / g (half1)
    int rowB = half * 64 + 32 + j;   // gate f (half0) / o (half1)

    float wA[32], wB[32];
    #pragma unroll
    for (int q = 0; q < 8; q++) {
        float4 va = *(const float4*)&w_hh0[rowA * 32 + 4 * q];
        float4 vb = *(const float4*)&w_hh0[rowB * 32 + 4 * q];
        wA[4*q] = va.x; wA[4*q+1] = va.y; wA[4*q+2] = va.z; wA[4*q+3] = va.w;
        wB[4*q] = vb.x; wB[4*q+1] = vb.y; wB[4*q+2] = vb.z; wB[4*q+3] = vb.w;
    }

    // layer-0 recurrence (input projections precomputed in k_proj0)
    float h = 0.0f, c = 0.0f;
    float h0s[T_STEPS];
    #pragma unroll
    for (int t = 0; t < T_STEPS; t++) {
        const float* g = &gx0[((size_t)n * T_STEPS + t) * 128];
        float gA0 = g[rowA], gB0 = g[rowB], gA1 = 0.0f, gB1 = 0.0f;
        #pragma unroll
        for (int k = 0; k < 16; k++) {
            float h0 = rdlane(h, k), h1 = rdlane(h, k + 16);
            gA0 = fmaf(h0, wA[k], gA0);      gA1 = fmaf(h1, wA[k + 16], gA1);
            gB0 = fmaf(h0, wB[k], gB0);      gB1 = fmaf(h1, wB[k + 16], gB1);
        }
        float gA = gA0 + gA1, gB = gB0 + gB1;
        float oA = __shfl_xor(gA, 32, 64);
        float oB = __shfl_xor(gB, 32, 64);
        float gi = half ? oA : gA;
        float gf = half ? oB : gB;
        float gg = half ? gA : oA;
        float go = half ? gB : oB;
        c = sigm(gf) * c + sigm(gi) * tanh_f(gg);
        h = sigm(go) * tanh_f(c);
        h0s[t] = h;
    }
    // layer-1 input projections from h0s (t-parallel, ILP-rich)
    #pragma unroll
    for (int q = 0; q < 8; q++) {
        float4 va = *(const float4*)&w_ih1[rowA * 32 + 4 * q];
        float4 vb = *(const float4*)&w_ih1[rowB * 32 + 4 * q];
        wA[4*q] = va.x; wA[4*q+1] = va.y; wA[4*q+2] = va.z; wA[4*q+3] = va.w;
        wB[4*q] = vb.x; wB[4*q+1] = vb.y; wB[4*q+2] = vb.z; wB[4*q+3] = vb.w;
    }
    float bA1 = b_ih1[rowA] + b_hh1[rowA];
    float bB1 = b_ih1[rowB] + b_hh1[rowB];
    float gxa1[T_STEPS], gxb1[T_STEPS];
    #pragma unroll
    for (int t = 0; t < T_STEPS; t++) {
        float a = bA1, b = bB1;
        #pragma unroll
        for (int k = 0; k < 32; k++) {
            float xk = rdlane(h0s[t], k);
            a = fmaf(xk, wA[k], a);
            b = fmaf(xk, wB[k], b);
        }
        gxa1[t] = a; gxb1[t] = b;
    }
    #pragma unroll
    for (int q = 0; q < 8; q++) {
        float4 va = *(const float4*)&w_hh1[rowA * 32 + 4 * q];
        float4 vb = *(const float4*)&w_hh1[rowB * 32 + 4 * q];
        wA[4*q] = va.x; wA[4*q+1] = va.y; wA[4*q+2] = va.z; wA[4*q+3] = va.w;
        wB[4*q] = vb.x; wB[4*q+1] = vb.y; wB[4*q+2] = vb.z; wB[4*q+3] = vb.w;
    }
    // layer-1 recurrence
    h = 0.0f; c = 0.0f;
    #pragma unroll
    for (int t = 0; t < T_STEPS; t++) {
        float gA0 = gxa1[t], gB0 = gxb1[t], gA1 = 0.0f, gB1 = 0.0f;
        #pragma unroll
        for (int k = 0; k < 16; k++) {
            float h0 = rdlane(h, k), h1 = rdlane(h, k + 16);
            gA0 = fmaf(h0, wA[k], gA0);      gA1 = fmaf(h1, wA[k + 16], gA1);
            gB0 = fmaf(h0, wB[k], gB0);      gB1 = fmaf(h1, wB[k + 16], gB1);
        }
        float gA = gA0 + gA1, gB = gB0 + gB1;
        float oA = __shfl_xor(gA, 32, 64);
        float oB = __shfl_xor(gB, 32, 64);
        float gi = half ? oA : gA;
        float gf = half ? oB : gB;
        float gg = half ? gA : oA;
        float go = half ? gB : oB;
        c = sigm(gf) * c + sigm(gi) * tanh_f(gg);
        h = sigm(go) * tanh_f(c);
    }
    // FC head: all lanes compute (o clamped), lanes 0..23 store.
    int o = (lane < OUT_F) ? lane : (OUT_F - 1);
    float fw[32];
    #pragma unroll
    for (int q = 0; q < 8; q++) {
        float4 v = *(const float4*)&fc_w[o * 32 + 4 * q];
        fw[4*q] = v.x; fw[4*q+1] = v.y; fw[4*q+2] = v.z; fw[4*q+3] = v.w;
    }
    float acc = fc_b[o];
    #pragma unroll
    for (int k = 0; k < 32; k++) {
        float hk = rdlane(h, k);
        acc = fmaf(hk, fw[k], acc);
    }
    if (lane < OUT_F) out[(size_t)n * OUT_F + lane] = acc;
}

// ---------------------------------------------------------------------------
extern "C" void kernel_launch(void* const* d_in, const int* in_sizes, int n_in,
                              void* d_out, int out_size, void* d_ws, size_t ws_size,
                              hipStream_t stream) {
    (void)in_sizes; (void)n_in; (void)out_size; (void)ws_size;
    const float* X       = (const float*)d_in[0];
    const int*   ei      = (const int*)d_in[1];
    const float* gat_w   = (const float*)d_in[2];
    const float* att_src = (const float*)d_in[3];
    const float* att_dst = (const float*)d_in[4];
    const float* gat_b   = (const float*)d_in[5];
    const float* w_ih0   = (const float*)d_in[6];
    const float* w_hh0   = (const float*)d_in[7];
    const float* b_ih0   = (const float*)d_in[8];
    const float* b_hh0   = (const float*)d_in[9];
    const float* w_ih1   = (const float*)d_in[10];
    const float* w_hh1   = (const float*)d_in[11];
    const float* b_ih1   = (const float*)d_in[12];
    const float* b_hh1   = (const float*)d_in[13];
    const float* fc_w    = (const float*)d_in[14];
    const float* fc_b    = (const float*)d_in[15];
    float* out = (float*)d_out;

    char* ws = (char*)d_ws;
    size_t off = 0;
    auto alloc_f = [&](size_t n) { float* p = (float*)(ws + off); off += n * sizeof(float); return p; };
    auto alloc_i = [&](size_t n) { int* p = (int*)(ws + off); off += n * sizeof(int); return p; };

    float*  gat_out = alloc_f((size_t)NT * HID);       // 1.15M f
    float*  gx0     = alloc_f((size_t)NT * 128);       // 4.61M f
    float2* Xt      = (float2*)alloc_f((size_t)NT * 2); // 72K f (8B-aligned)
    float*  proj    = alloc_f(32);
    int* deg       = alloc_i(N_NODES);
    int* row_start = alloc_i(N_NODES + 1);
    int* cursor    = alloc_i(N_NODES);
    int* csr_src   = alloc_i(E_TOT);

    k_init<<<13 + (NT + 255) / 256, 256, 0, stream>>>(deg, gat_w, att_src, att_dst,
                                                      proj, X, Xt);
    k_deg<<<(E_TOT + 255) / 256, 256, 0, stream>>>(ei, deg);
    k_scan<<<1, 256, 0, stream>>>(deg, row_start, cursor);
    k_scatter<<<(E_TOT + 255) / 256, 256, 0, stream>>>(ei, cursor, csr_src);
    k_gat<<<NT / 4, 256, 0, stream>>>(Xt, row_start, csr_src, proj,
                                      gat_w, gat_b, gat_out);
    k_proj0<<<NT / 2, 256, 0, stream>>>(gat_out, w_ih0, b_ih0, b_hh0, gx0);
    k_lstm<<<N_NODES, 64, 0, stream>>>(gx0, w_hh0, w_ih1, w_hh1, b_ih1, b_hh1,
                                       fc_w, fc_b, out);
}

// Round 9
// 165.455 us; speedup vs baseline: 1.5598x; 1.5598x over previous
//
#include <hip/hip_runtime.h>
#include <math.h>

#define N_NODES 3000
#define T_STEPS 12
#define F_INP 2
#define HEADS 8
#define HID 32
#define E_EDGES 32000
#define E_TOT (E_EDGES + N_NODES)   // 35000 with self-loops
#define NEG_SLOPE 0.2f
#define OUT_F 24                    // F_OUT * T_OUT
#define CHUNKS 8                    // 8 slots x 8 chunks = 64 edges in regs
#define NT (N_NODES * T_STEPS)      // 36000
#define WROW 33                     // LDS row stride (+1 pad -> conflict-free)

__device__ __forceinline__ float sigm(float x) {
    return 1.0f / (1.0f + __expf(-x));
}
__device__ __forceinline__ float tanh_f(float x) {
    return 1.0f - 2.0f / (__expf(2.0f * x) + 1.0f);
}
// broadcast lane l's value via scalar pipe (v_readlane). CONVERGENT: call at
// full exec only (round-4 post-mortem).
__device__ __forceinline__ float rdlane(float v, int l) {
    return __int_as_float(__builtin_amdgcn_readlane(__float_as_int(v), l));
}

// ---------------------------------------------------------------------------
// k_init: blocks 0..11 zero deg; block 12 computes proj; blocks 13.. build
// Xt[t][n] = (x0,x1) so k_gat's per-edge gathers hit a 24 KB L1-resident
// plane per t instead of scattering over the full 288 KB X.
// ---------------------------------------------------------------------------
__global__ void k_init(int* __restrict__ deg,
                       const float* __restrict__ gat_w,
                       const float* __restrict__ att_src,
                       const float* __restrict__ att_dst,
                       float* __restrict__ proj,
                       const float* __restrict__ X,
                       float2* __restrict__ Xt) {
    int b = blockIdx.x;
    if (b < 12) {
        int i = b * 256 + threadIdx.x;
        if (i < N_NODES) deg[i] = 0;
    } else if (b == 12) {
        int tid = threadIdx.x;
        if (tid < 32) {
            int h = tid & 7, w = tid >> 3;
            const float* att = (w < 2) ? att_src : att_dst;
            int f = w & 1;
            float s = 0.0f;
            for (int c = 0; c < 32; c++)
                s += gat_w[((h * 32 + c) * 2) + f] * att[h * 32 + c];
            proj[w * 8 + h] = s;
        }
    } else {
        int i = (b - 13) * 256 + threadIdx.x;   // i = n*T + t
        if (i < NT) {
            int n = i / T_STEPS, t = i - n * T_STEPS;
            float2 v = *(const float2*)&X[(size_t)i * 2];
            Xt[(size_t)t * N_NODES + n] = v;
        }
    }
}

__global__ void k_deg(const int* __restrict__ ei, int* __restrict__ deg) {
    int i = blockIdx.x * blockDim.x + threadIdx.x;
    if (i >= E_TOT) return;
    int d = (i < E_EDGES) ? ei[E_EDGES + i] : (i - E_EDGES);
    atomicAdd(&deg[d], 1);
}

__global__ __launch_bounds__(256) void k_scan(const int* __restrict__ deg,
                                              int* __restrict__ row_start,
                                              int* __restrict__ cursor) {
    __shared__ int part[256];
    int tid = threadIdx.x;
    const int CH = (N_NODES + 255) / 256;   // 12
    int base = tid * CH;
    int s = 0;
    for (int i = 0; i < CH; i++) {
        int idx = base + i;
        if (idx < N_NODES) s += deg[idx];
    }
    part[tid] = s;
    __syncthreads();
    if (tid == 0) {
        int run = 0;
        for (int i = 0; i < 256; i++) { int tmp = part[i]; part[i] = run; run += tmp; }
        row_start[N_NODES] = run;           // == E_TOT
    }
    __syncthreads();
    int off = part[tid];
    for (int i = 0; i < CH; i++) {
        int idx = base + i;
        if (idx < N_NODES) {
            row_start[idx] = off;
            cursor[idx] = off;
            off += deg[idx];
        }
    }
}

__global__ void k_scatter(const int* __restrict__ ei, int* __restrict__ cursor,
                          int* __restrict__ csr_src) {
    int i = blockIdx.x * blockDim.x + threadIdx.x;
    if (i >= E_TOT) return;
    int s, d;
    if (i < E_EDGES) { s = ei[i]; d = ei[E_EDGES + i]; }
    else             { s = i - E_EDGES; d = s; }
    int pos = atomicAdd(&cursor[d], 1);
    csr_src[pos] = s;
}

// ---------------------------------------------------------------------------
// k_gat: one wave64 per (t,n). lanes = 8 heads x 8 slots. Edge values in
// registers, reductions via shfl_xor(1,2,4); head-sum broadcast via
// v_readlane AT FULL EXEC. Reads Xt (L1-resident 24 KB plane per t).
// gat_out layout: [n][t][c]
// ---------------------------------------------------------------------------
__global__ __launch_bounds__(256) void k_gat(const float2* __restrict__ Xt,
                                             const int* __restrict__ row_start,
                                             const int* __restrict__ csr_src,
                                             const float* __restrict__ proj,
                                             const float* __restrict__ gat_w,
                                             const float* __restrict__ gat_b,
                                             float* __restrict__ gat_out) {
    int pair = blockIdx.x * 4 + (threadIdx.x >> 6);   // t*N + n
    int t = pair / N_NODES, n = pair - t * N_NODES;
    int lane = threadIdx.x & 63;
    int h = lane >> 3, slot = lane & 7;
    int rs = row_start[n];
    int deg = row_start[n + 1] - rs;     // >= 1 (self-loop)
    const float2* Xp = Xt + (size_t)t * N_NODES;
    float ps0 = proj[h], ps1 = proj[8 + h];
    float pd0 = proj[16 + h], pd1 = proj[24 + h];
    float2 xd = Xp[n];
    float ad = fmaf(xd.x, pd0, xd.y * pd1);

    float x0c[CHUNKS], x1c[CHUNKS], sc[CHUNKS];
    float m = -1e30f;
    #pragma unroll
    for (int c = 0; c < CHUNKS; c++) {
        if (8 * c < deg) {                       // wave-uniform branch
            int e = slot + 8 * c;
            int idx = rs + (e < deg ? e : deg - 1);
            int src = csr_src[idx];
            float2 xv = Xp[src];
            x0c[c] = xv.x; x1c[c] = xv.y;
            float s = fmaf(xv.x, ps0, fmaf(xv.y, ps1, ad));
            s = (s > 0.0f) ? s : NEG_SLOPE * s;
            sc[c] = (e < deg) ? s : -1e30f;
            m = fmaxf(m, sc[c]);
        } else { x0c[c] = 0.0f; x1c[c] = 0.0f; sc[c] = -1e30f; }
    }
    // deg > 64 fallback (never taken for this graph; wave-uniform)
    for (int e = 64 + slot; e < deg; e += 8) {
        float2 xv = Xp[csr_src[rs + e]];
        float s = fmaf(xv.x, ps0, fmaf(xv.y, ps1, ad));
        s = (s > 0.0f) ? s : NEG_SLOPE * s;
        m = fmaxf(m, s);
    }
    m = fmaxf(m, __shfl_xor(m, 1, 64));
    m = fmaxf(m, __shfl_xor(m, 2, 64));
    m = fmaxf(m, __shfl_xor(m, 4, 64));

    float den = 0.0f, S0 = 0.0f, S1 = 0.0f;
    #pragma unroll
    for (int c = 0; c < CHUNKS; c++) {
        if (8 * c < deg) {
            float a = __expf(sc[c] - m);          // masked slots: exp(-1e30)=0
            den += a;
            S0 = fmaf(a, x0c[c], S0);
            S1 = fmaf(a, x1c[c], S1);
        }
    }
    for (int e = 64 + slot; e < deg; e += 8) {    // fallback recompute
        float2 xv = Xp[csr_src[rs + e]];
        float s = fmaf(xv.x, ps0, fmaf(xv.y, ps1, ad));
        s = (s > 0.0f) ? s : NEG_SLOPE * s;
        float a = __expf(s - m);
        den += a; S0 = fmaf(a, xv.x, S0); S1 = fmaf(a, xv.y, S1);
    }
    #pragma unroll
    for (int mm = 1; mm <= 4; mm <<= 1) {
        den += __shfl_xor(den, mm, 64);
        S0  += __shfl_xor(S0,  mm, 64);
        S1  += __shfl_xor(S1,  mm, 64);
    }
    float inv = 0.125f / den;
    float v0 = S0 * inv, v1 = S1 * inv;

    // per-head broadcasts at FULL EXEC (readlane is convergent; round-4 fix)
    float a0[HEADS], a1[HEADS];
    #pragma unroll
    for (int hh = 0; hh < HEADS; hh++) {
        a0[hh] = rdlane(v0, hh * 8);
        a1[hh] = rdlane(v1, hh * 8);
    }

    // branch-free projection: all lanes compute, lanes 0..31 store
    int cc = lane & 31;
    float acc = gat_b[cc];
    #pragma unroll
    for (int hh = 0; hh < HEADS; hh++) {
        float2 g = *(const float2*)&gat_w[(hh * 32 + cc) * 2];
        acc = fmaf(a0[hh], g.x, fmaf(a1[hh], g.y, acc));
    }
    if (lane < 32)
        gat_out[((size_t)n * T_STEPS + t) * HID + cc] = acc;
}

// ---------------------------------------------------------------------------
// k_lstm v3: fused 2-layer LSTM + FC. Block = 256 thr = 4 waves = 4 nodes.
// Weight matrices are staged COALESCED into one LDS buffer phase-by-phase
// (w_ih0 -> w_hh0 -> w_ih1 -> w_hh1 -> fc_w) -- round-7 lesson: per-lane
// row-strided global loads cost 64 cache lines per instruction (85 us in
// k_proj0). LDS rows padded to stride 33 -> per-lane row reads hit bank
// (row+k)%32: conflict-free. Split-gate waves: half 0 owns (i,f), half 1
// owns (g,o); h broadcast via v_readlane; split-k 2x16 fma chains.
// __launch_bounds__(256,3): ~130 live floats/lane need the 170-VGPR budget
// (round-6's default 68 VGPR caused AGPR churn, 85 us).
// ---------------------------------------------------------------------------
__global__ __launch_bounds__(256, 3)
void k_lstm(const float* __restrict__ gat_out,  // [n][t][32]
            const float* __restrict__ w_ih0,
            const float* __restrict__ w_hh0,
            const float* __restrict__ b_ih0,
            const float* __restrict__ b_hh0,
            const float* __restrict__ w_ih1,
            const float* __restrict__ w_hh1,
            const float* __restrict__ b_ih1,
            const float* __restrict__ b_hh1,
            const float* __restrict__ fc_w,
            const float* __restrict__ fc_b,
            float* __restrict__ out) {          // [n][24]
    __shared__ float wl[128 * WROW];            // 16.9 KB, reused 5x
    int tid = threadIdx.x;
    int lane = tid & 63;
    int n = blockIdx.x * 4 + (tid >> 6);
    int j = lane & 31, half = lane >> 5;
    int rowA = half * 64 + j;        // gate i (half0) / g (half1)
    int rowB = rowA + 32;            // gate f (half0) / o (half1)

    // coalesced global -> LDS stage (float4 loads, scalar LDS writes)
    auto stage = [&](const float* __restrict__ src, int nfloats) {
        for (int base = tid * 4; base < nfloats; base += 1024) {
            float4 v = *(const float4*)&src[base];
            float* d = &wl[(base >> 5) * WROW + (base & 31)];
            d[0] = v.x; d[1] = v.y; d[2] = v.z; d[3] = v.w;
        }
    };
    // per-lane row fetch from LDS (conflict-free: bank = (row+k)%32)
    auto loadrows = [&](float* wA, float* wB) {
        #pragma unroll
        for (int k = 0; k < 32; k++) wA[k] = wl[rowA * WROW + k];
        #pragma unroll
        for (int k = 0; k < 32; k++) wB[k] = wl[rowB * WROW + k];
    };

    float wA[32], wB[32];

    // ---- phase 1: layer-0 input projections (t-parallel, ILP-rich) ----
    stage(w_ih0, 4096);
    __syncthreads();
    loadrows(wA, wB);
    float bA = b_ih0[rowA] + b_hh0[rowA];
    float bB = b_ih0[rowB] + b_hh0[rowB];
    float xrow[T_STEPS];
    #pragma unroll
    for (int t = 0; t < T_STEPS; t++)
        xrow[t] = gat_out[((size_t)n * T_STEPS + t) * HID + j];
    float gxa[T_STEPS], gxb[T_STEPS];
    #pragma unroll
    for (int t = 0; t < T_STEPS; t++) {
        float a = bA, b = bB;
        #pragma unroll
        for (int k = 0; k < 32; k++) {
            float xk = rdlane(xrow[t], k);
            a = fmaf(xk, wA[k], a);
            b = fmaf(xk, wB[k], b);
        }
        gxa[t] = a; gxb[t] = b;
    }
    __syncthreads();

    // ---- phase 2: layer-0 recurrence ----
    stage(w_hh0, 4096);
    __syncthreads();
    loadrows(wA, wB);
    float h = 0.0f, c = 0.0f;
    float h0s[T_STEPS];
    #pragma unroll
    for (int t = 0; t < T_STEPS; t++) {
        float gA0 = gxa[t], gB0 = gxb[t], gA1 = 0.0f, gB1 = 0.0f;
        #pragma unroll
        for (int k = 0; k < 16; k++) {
            float h0 = rdlane(h, k), h1 = rdlane(h, k + 16);
            gA0 = fmaf(h0, wA[k], gA0);      gA1 = fmaf(h1, wA[k + 16], gA1);
            gB0 = fmaf(h0, wB[k], gB0);      gB1 = fmaf(h1, wB[k + 16], gB1);
        }
        float gA = gA0 + gA1, gB = gB0 + gB1;
        float oA = __shfl_xor(gA, 32, 64);
        float oB = __shfl_xor(gB, 32, 64);
        float gi = half ? oA : gA;
        float gf = half ? oB : gB;
        float gg = half ? gA : oA;
        float go = half ? gB : oB;
        c = sigm(gf) * c + sigm(gi) * tanh_f(gg);
        h = sigm(go) * tanh_f(c);
        h0s[t] = h;
    }
    __syncthreads();

    // ---- phase 3: layer-1 input projections from h0s ----
    stage(w_ih1, 4096);
    __syncthreads();
    loadrows(wA, wB);
    float bA1 = b_ih1[rowA] + b_hh1[rowA];
    float bB1 = b_ih1[rowB] + b_hh1[rowB];
    #pragma unroll
    for (int t = 0; t < T_STEPS; t++) {
        float a = bA1, b = bB1;
        #pragma unroll
        for (int k = 0; k < 32; k++) {
            float xk = rdlane(h0s[t], k);
            a = fmaf(xk, wA[k], a);
            b = fmaf(xk, wB[k], b);
        }
        gxa[t] = a; gxb[t] = b;
    }
    __syncthreads();

    // ---- phase 4: layer-1 recurrence ----
    stage(w_hh1, 4096);
    __syncthreads();
    loadrows(wA, wB);
    h = 0.0f; c = 0.0f;
    #pragma unroll
    for (int t = 0; t < T_STEPS; t++) {
        float gA0 = gxa[t], gB0 = gxb[t], gA1 = 0.0f, gB1 = 0.0f;
        #pragma unroll
        for (int k = 0; k < 16; k++) {
            float h0 = rdlane(h, k), h1 = rdlane(h, k + 16);
            gA0 = fmaf(h0, wA[k], gA0);      gA1 = fmaf(h1, wA[k + 16], gA1);
            gB0 = fmaf(h0, wB[k], gB0);      gB1 = fmaf(h1, wB[k + 16], gB1);
        }
        float gA = gA0 + gA1, gB = gB0 + gB1;
        float oA = __shfl_xor(gA, 32, 64);
        float oB = __shfl_xor(gB, 32, 64);
        float gi = half ? oA : gA;
        float gf = half ? oB : gB;
        float gg = half ? gA : oA;
        float go = half ? gB : oB;
        c = sigm(gf) * c + sigm(gi) * tanh_f(gg);
        h = sigm(go) * tanh_f(c);
    }
    __syncthreads();

    // ---- phase 5: FC head ----
    stage(fc_w, OUT_F * HID);    // 768 floats
    __syncthreads();
    int o = (lane < OUT_F) ? lane : (OUT_F - 1);   // lanes >=24 broadcast row 23
    float acc = fc_b[o];
    #pragma unroll
    for (int k = 0; k < 32; k++) {
        float hk = rdlane(h, k);
        acc = fmaf(hk, wl[o * WROW + k], acc);
    }
    if (lane < OUT_F) out[(size_t)n * OUT_F + lane] = acc;
}

// ---------------------------------------------------------------------------
extern "C" void kernel_launch(void* const* d_in, const int* in_sizes, int n_in,
                              void* d_out, int out_size, void* d_ws, size_t ws_size,
                              hipStream_t stream) {
    (void)in_sizes; (void)n_in; (void)out_size; (void)ws_size;
    const float* X       = (const float*)d_in[0];
    const int*   ei      = (const int*)d_in[1];
    const float* gat_w   = (const float*)d_in[2];
    const float* att_src = (const float*)d_in[3];
    const float* att_dst = (const float*)d_in[4];
    const float* gat_b   = (const float*)d_in[5];
    const float* w_ih0   = (const float*)d_in[6];
    const float* w_hh0   = (const float*)d_in[7];
    const float* b_ih0   = (const float*)d_in[8];
    const float* b_hh0   = (const float*)d_in[9];
    const float* w_ih1   = (const float*)d_in[10];
    const float* w_hh1   = (const float*)d_in[11];
    const float* b_ih1   = (const float*)d_in[12];
    const float* b_hh1   = (const float*)d_in[13];
    const float* fc_w    = (const float*)d_in[14];
    const float* fc_b    = (const float*)d_in[15];
    float* out = (float*)d_out;

    char* ws = (char*)d_ws;
    size_t off = 0;
    auto alloc_f = [&](size_t n) { float* p = (float*)(ws + off); off += n * sizeof(float); return p; };
    auto alloc_i = [&](size_t n) { int* p = (int*)(ws + off); off += n * sizeof(int); return p; };

    float*  gat_out = alloc_f((size_t)NT * HID);        // 4.6 MB
    float2* Xt      = (float2*)alloc_f((size_t)NT * 2); // 288 KB
    float*  proj    = alloc_f(32);
    int* deg       = alloc_i(N_NODES);
    int* row_start = alloc_i(N_NODES + 1);
    int* cursor    = alloc_i(N_NODES);
    int* csr_src   = alloc_i(E_TOT);

    k_init<<<13 + (NT + 255) / 256, 256, 0, stream>>>(deg, gat_w, att_src, att_dst,
                                                      proj, X, Xt);
    k_deg<<<(E_TOT + 255) / 256, 256, 0, stream>>>(ei, deg);
    k_scan<<<1, 256, 0, stream>>>(deg, row_start, cursor);
    k_scatter<<<(E_TOT + 255) / 256, 256, 0, stream>>>(ei, cursor, csr_src);
    k_gat<<<NT / 4, 256, 0, stream>>>(Xt, row_start, csr_src, proj,
                                      gat_w, gat_b, gat_out);
    k_lstm<<<N_NODES / 4, 256, 0, stream>>>(gat_out, w_ih0, w_hh0, b_ih0, b_hh0,
                                            w_ih1, w_hh1, b_ih1, b_hh1,
                                            fc_w, fc_b, out);
}

// Round 10
// 162.092 us; speedup vs baseline: 1.5922x; 1.0207x over previous
//
#include <hip/hip_runtime.h>
#include <math.h>

#define N_NODES 3000
#define T_STEPS 12
#define F_INP 2
#define HEADS 8
#define HID 32
#define E_EDGES 32000
#define E_TOT (E_EDGES + N_NODES)   // 35000 with self-loops
#define NEG_SLOPE 0.2f
#define OUT_F 24                    // F_OUT * T_OUT
#define CHUNKS 8                    // 8 slots x 8 chunks = 64 edges in regs
#define NT (N_NODES * T_STEPS)      // 36000
#define WROW 33                     // LDS row stride (+1 pad -> conflict-free)

__device__ __forceinline__ float sigm(float x) {
    return 1.0f / (1.0f + __expf(-x));
}
__device__ __forceinline__ float tanh_f(float x) {
    return 1.0f - 2.0f / (__expf(2.0f * x) + 1.0f);
}
// broadcast lane l's value via scalar pipe (v_readlane). CONVERGENT: call at
// full exec only (round-4 post-mortem).
__device__ __forceinline__ float rdlane(float v, int l) {
    return __int_as_float(__builtin_amdgcn_readlane(__float_as_int(v), l));
}

// ---------------------------------------------------------------------------
// k_init: blocks 0..11 zero deg; block 12 computes proj; blocks 13.. build
// Xt[t][n] = (x0,x1) so k_gat's per-edge gathers hit a 24 KB L1-resident
// plane per t instead of scattering over the full 288 KB X.
// ---------------------------------------------------------------------------
__global__ void k_init(int* __restrict__ deg,
                       const float* __restrict__ gat_w,
                       const float* __restrict__ att_src,
                       const float* __restrict__ att_dst,
                       float* __restrict__ proj,
                       const float* __restrict__ X,
                       float2* __restrict__ Xt) {
    int b = blockIdx.x;
    if (b < 12) {
        int i = b * 256 + threadIdx.x;
        if (i < N_NODES) deg[i] = 0;
    } else if (b == 12) {
        int tid = threadIdx.x;
        if (tid < 32) {
            int h = tid & 7, w = tid >> 3;
            const float* att = (w < 2) ? att_src : att_dst;
            int f = w & 1;
            float s = 0.0f;
            for (int c = 0; c < 32; c++)
                s += gat_w[((h * 32 + c) * 2) + f] * att[h * 32 + c];
            proj[w * 8 + h] = s;
        }
    } else {
        int i = (b - 13) * 256 + threadIdx.x;   // i = n*T + t
        if (i < NT) {
            int n = i / T_STEPS, t = i - n * T_STEPS;
            float2 v = *(const float2*)&X[(size_t)i * 2];
            Xt[(size_t)t * N_NODES + n] = v;
        }
    }
}

__global__ void k_deg(const int* __restrict__ ei, int* __restrict__ deg) {
    int i = blockIdx.x * blockDim.x + threadIdx.x;
    if (i >= E_TOT) return;
    int d = (i < E_EDGES) ? ei[E_EDGES + i] : (i - E_EDGES);
    atomicAdd(&deg[d], 1);
}

__global__ __launch_bounds__(256) void k_scan(const int* __restrict__ deg,
                                              int* __restrict__ row_start,
                                              int* __restrict__ cursor) {
    __shared__ int part[256];
    int tid = threadIdx.x;
    const int CH = (N_NODES + 255) / 256;   // 12
    int base = tid * CH;
    int s = 0;
    for (int i = 0; i < CH; i++) {
        int idx = base + i;
        if (idx < N_NODES) s += deg[idx];
    }
    part[tid] = s;
    __syncthreads();
    if (tid == 0) {
        int run = 0;
        for (int i = 0; i < 256; i++) { int tmp = part[i]; part[i] = run; run += tmp; }
        row_start[N_NODES] = run;           // == E_TOT
    }
    __syncthreads();
    int off = part[tid];
    for (int i = 0; i < CH; i++) {
        int idx = base + i;
        if (idx < N_NODES) {
            row_start[idx] = off;
            cursor[idx] = off;
            off += deg[idx];
        }
    }
}

__global__ void k_scatter(const int* __restrict__ ei, int* __restrict__ cursor,
                          int* __restrict__ csr_src) {
    int i = blockIdx.x * blockDim.x + threadIdx.x;
    if (i >= E_TOT) return;
    int s, d;
    if (i < E_EDGES) { s = ei[i]; d = ei[E_EDGES + i]; }
    else             { s = i - E_EDGES; d = s; }
    int pos = atomicAdd(&cursor[d], 1);
    csr_src[pos] = s;
}

// ---------------------------------------------------------------------------
// k_gat: one wave64 per (t,n). lanes = 8 heads x 8 slots. Edge values in
// registers, reductions via shfl_xor(1,2,4); head-sum broadcast via
// v_readlane AT FULL EXEC. Reads Xt (L1-resident 24 KB plane per t).
// gat_out layout: [n][t][c]
// ---------------------------------------------------------------------------
__global__ __launch_bounds__(256) void k_gat(const float2* __restrict__ Xt,
                                             const int* __restrict__ row_start,
                                             const int* __restrict__ csr_src,
                                             const float* __restrict__ proj,
                                             const float* __restrict__ gat_w,
                                             const float* __restrict__ gat_b,
                                             float* __restrict__ gat_out) {
    int pair = blockIdx.x * 4 + (threadIdx.x >> 6);   // t*N + n
    int t = pair / N_NODES, n = pair - t * N_NODES;
    int lane = threadIdx.x & 63;
    int h = lane >> 3, slot = lane & 7;
    int rs = row_start[n];
    int deg = row_start[n + 1] - rs;     // >= 1 (self-loop)
    const float2* Xp = Xt + (size_t)t * N_NODES;
    float ps0 = proj[h], ps1 = proj[8 + h];
    float pd0 = proj[16 + h], pd1 = proj[24 + h];
    float2 xd = Xp[n];
    float ad = fmaf(xd.x, pd0, xd.y * pd1);

    float x0c[CHUNKS], x1c[CHUNKS], sc[CHUNKS];
    float m = -1e30f;
    #pragma unroll
    for (int c = 0; c < CHUNKS; c++) {
        if (8 * c < deg) {                       // wave-uniform branch
            int e = slot + 8 * c;
            int idx = rs + (e < deg ? e : deg - 1);
            int src = csr_src[idx];
            float2 xv = Xp[src];
            x0c[c] = xv.x; x1c[c] = xv.y;
            float s = fmaf(xv.x, ps0, fmaf(xv.y, ps1, ad));
            s = (s > 0.0f) ? s : NEG_SLOPE * s;
            sc[c] = (e < deg) ? s : -1e30f;
            m = fmaxf(m, sc[c]);
        } else { x0c[c] = 0.0f; x1c[c] = 0.0f; sc[c] = -1e30f; }
    }
    // deg > 64 fallback (never taken for this graph; wave-uniform)
    for (int e = 64 + slot; e < deg; e += 8) {
        float2 xv = Xp[csr_src[rs + e]];
        float s = fmaf(xv.x, ps0, fmaf(xv.y, ps1, ad));
        s = (s > 0.0f) ? s : NEG_SLOPE * s;
        m = fmaxf(m, s);
    }
    m = fmaxf(m, __shfl_xor(m, 1, 64));
    m = fmaxf(m, __shfl_xor(m, 2, 64));
    m = fmaxf(m, __shfl_xor(m, 4, 64));

    float den = 0.0f, S0 = 0.0f, S1 = 0.0f;
    #pragma unroll
    for (int c = 0; c < CHUNKS; c++) {
        if (8 * c < deg) {
            float a = __expf(sc[c] - m);          // masked slots: exp(-1e30)=0
            den += a;
            S0 = fmaf(a, x0c[c], S0);
            S1 = fmaf(a, x1c[c], S1);
        }
    }
    for (int e = 64 + slot; e < deg; e += 8) {    // fallback recompute
        float2 xv = Xp[csr_src[rs + e]];
        float s = fmaf(xv.x, ps0, fmaf(xv.y, ps1, ad));
        s = (s > 0.0f) ? s : NEG_SLOPE * s;
        float a = __expf(s - m);
        den += a; S0 = fmaf(a, xv.x, S0); S1 = fmaf(a, xv.y, S1);
    }
    #pragma unroll
    for (int mm = 1; mm <= 4; mm <<= 1) {
        den += __shfl_xor(den, mm, 64);
        S0  += __shfl_xor(S0,  mm, 64);
        S1  += __shfl_xor(S1,  mm, 64);
    }
    float inv = 0.125f / den;
    float v0 = S0 * inv, v1 = S1 * inv;

    // per-head broadcasts at FULL EXEC (readlane is convergent; round-4 fix)
    float a0[HEADS], a1[HEADS];
    #pragma unroll
    for (int hh = 0; hh < HEADS; hh++) {
        a0[hh] = rdlane(v0, hh * 8);
        a1[hh] = rdlane(v1, hh * 8);
    }

    // branch-free projection: all lanes compute, lanes 0..31 store
    int cc = lane & 31;
    float acc = gat_b[cc];
    #pragma unroll
    for (int hh = 0; hh < HEADS; hh++) {
        float2 g = *(const float2*)&gat_w[(hh * 32 + cc) * 2];
        acc = fmaf(a0[hh], g.x, fmaf(a1[hh], g.y, acc));
    }
    if (lane < 32)
        gat_out[((size_t)n * T_STEPS + t) * HID + cc] = acc;
}

// ---------------------------------------------------------------------------
// k_lstm v4: fused 2-layer LSTM + FC. Block = 256 thr = 4 waves = 4 nodes.
// Round-9 post-mortem: VGPR_Count=56 with ~110 live floats => compiler put
// the state arrays (gxa/gxb/h0s/xrow) in AGPRs; every access paid a
// v_accvgpr copy (measured 12.4k VALU instr/wave vs 5.4k hand-count).
// v4 moves ALL per-thread state to thread-private LDS slots [t][tid]
// (bank-conflict-free, no cross-lane access -- rdlane does cross-lane) and
// de-unrolls the t-loops. Live regs ~80 (wA/wB + misc) -> pure VGPR.
// Weights still staged coalesced to LDS phase-by-phase (round-7 lesson:
// per-lane row-strided global loads = 64 cache lines/instr).
// LDS/block = 16.9 (wl) + 24 (gx) + 12 (h) = 52.5 KiB -> 3 blocks/CU.
// ---------------------------------------------------------------------------
__global__ __launch_bounds__(256, 3)
void k_lstm(const float* __restrict__ gat_out,  // [n][t][32]
            const float* __restrict__ w_ih0,
            const float* __restrict__ w_hh0,
            const float* __restrict__ b_ih0,
            const float* __restrict__ b_hh0,
            const float* __restrict__ w_ih1,
            const float* __restrict__ w_hh1,
            const float* __restrict__ b_ih1,
            const float* __restrict__ b_hh1,
            const float* __restrict__ fc_w,
            const float* __restrict__ fc_b,
            float* __restrict__ out) {          // [n][24]
    __shared__ float wl[128 * WROW];            // 16.9 KB, reused 5x
    __shared__ float gxa_l[T_STEPS][256];       // 12 KB, thread-private slots
    __shared__ float gxb_l[T_STEPS][256];       // 12 KB
    __shared__ float h_l[T_STEPS][256];         // 12 KB
    int tid = threadIdx.x;
    int lane = tid & 63;
    int n = blockIdx.x * 4 + (tid >> 6);
    int j = lane & 31, half = lane >> 5;
    int rowA = half * 64 + j;        // gate i (half0) / g (half1)
    int rowB = rowA + 32;            // gate f (half0) / o (half1)

    // coalesced global -> LDS stage (float4 loads, scalar LDS writes)
    auto stage = [&](const float* __restrict__ src, int nfloats) {
        for (int base = tid * 4; base < nfloats; base += 1024) {
            float4 v = *(const float4*)&src[base];
            float* d = &wl[(base >> 5) * WROW + (base & 31)];
            d[0] = v.x; d[1] = v.y; d[2] = v.z; d[3] = v.w;
        }
    };
    // per-lane row fetch from LDS (conflict-free: bank = (row+k)%32)
    auto loadrows = [&](float* wA, float* wB) {
        #pragma unroll
        for (int k = 0; k < 32; k++) wA[k] = wl[rowA * WROW + k];
        #pragma unroll
        for (int k = 0; k < 32; k++) wB[k] = wl[rowB * WROW + k];
    };

    float wA[32], wB[32];

    // ---- phase 1: layer-0 input projections -> gx LDS ----
    stage(w_ih0, 4096);
    __syncthreads();
    loadrows(wA, wB);
    {
        float bA = b_ih0[rowA] + b_hh0[rowA];
        float bB = b_ih0[rowB] + b_hh0[rowB];
        #pragma unroll 2
        for (int t = 0; t < T_STEPS; t++) {
            float x = gat_out[((size_t)n * T_STEPS + t) * HID + j];
            float a = bA, b = bB;
            #pragma unroll
            for (int k = 0; k < 32; k++) {
                float xk = rdlane(x, k);
                a = fmaf(xk, wA[k], a);
                b = fmaf(xk, wB[k], b);
            }
            gxa_l[t][tid] = a; gxb_l[t][tid] = b;
        }
    }
    __syncthreads();

    // ---- phase 2: layer-0 recurrence (h -> h_l) ----
    stage(w_hh0, 4096);
    __syncthreads();
    loadrows(wA, wB);
    {
        float h = 0.0f, c = 0.0f;
        #pragma unroll 1
        for (int t = 0; t < T_STEPS; t++) {
            float gA0 = gxa_l[t][tid], gB0 = gxb_l[t][tid];
            float gA1 = 0.0f, gB1 = 0.0f;
            #pragma unroll
            for (int k = 0; k < 16; k++) {
                float h0 = rdlane(h, k), h1 = rdlane(h, k + 16);
                gA0 = fmaf(h0, wA[k], gA0);      gA1 = fmaf(h1, wA[k + 16], gA1);
                gB0 = fmaf(h0, wB[k], gB0);      gB1 = fmaf(h1, wB[k + 16], gB1);
            }
            float gA = gA0 + gA1, gB = gB0 + gB1;
            float oA = __shfl_xor(gA, 32, 64);
            float oB = __shfl_xor(gB, 32, 64);
            float gi = half ? oA : gA;
            float gf = half ? oB : gB;
            float gg = half ? gA : oA;
            float go = half ? gB : oB;
            c = sigm(gf) * c + sigm(gi) * tanh_f(gg);
            h = sigm(go) * tanh_f(c);
            h_l[t][tid] = h;
        }
    }
    __syncthreads();

    // ---- phase 3: layer-1 input projections from h_l -> gx LDS ----
    stage(w_ih1, 4096);
    __syncthreads();
    loadrows(wA, wB);
    {
        float bA = b_ih1[rowA] + b_hh1[rowA];
        float bB = b_ih1[rowB] + b_hh1[rowB];
        #pragma unroll 2
        for (int t = 0; t < T_STEPS; t++) {
            float x = h_l[t][tid];
            float a = bA, b = bB;
            #pragma unroll
            for (int k = 0; k < 32; k++) {
                float xk = rdlane(x, k);
                a = fmaf(xk, wA[k], a);
                b = fmaf(xk, wB[k], b);
            }
            gxa_l[t][tid] = a; gxb_l[t][tid] = b;
        }
    }
    __syncthreads();

    // ---- phase 4: layer-1 recurrence ----
    stage(w_hh1, 4096);
    __syncthreads();
    loadrows(wA, wB);
    float h = 0.0f;
    {
        float c = 0.0f;
        #pragma unroll 1
        for (int t = 0; t < T_STEPS; t++) {
            float gA0 = gxa_l[t][tid], gB0 = gxb_l[t][tid];
            float gA1 = 0.0f, gB1 = 0.0f;
            #pragma unroll
            for (int k = 0; k < 16; k++) {
                float h0 = rdlane(h, k), h1 = rdlane(h, k + 16);
                gA0 = fmaf(h0, wA[k], gA0);      gA1 = fmaf(h1, wA[k + 16], gA1);
                gB0 = fmaf(h0, wB[k], gB0);      gB1 = fmaf(h1, wB[k + 16], gB1);
            }
            float gA = gA0 + gA1, gB = gB0 + gB1;
            float oA = __shfl_xor(gA, 32, 64);
            float oB = __shfl_xor(gB, 32, 64);
            float gi = half ? oA : gA;
            float gf = half ? oB : gB;
            float gg = half ? gA : oA;
            float go = half ? gB : oB;
            c = sigm(gf) * c + sigm(gi) * tanh_f(gg);
            h = sigm(go) * tanh_f(c);
        }
    }
    __syncthreads();

    // ---- phase 5: FC head ----
    stage(fc_w, OUT_F * HID);    // 768 floats
    __syncthreads();
    int o = (lane < OUT_F) ? lane : (OUT_F - 1);   // lanes >=24 broadcast row 23
    float acc = fc_b[o];
    #pragma unroll
    for (int k = 0; k < 32; k++) {
        float hk = rdlane(h, k);
        acc = fmaf(hk, wl[o * WROW + k], acc);
    }
    if (lane < OUT_F) out[(size_t)n * OUT_F + lane] = acc;
}

// ---------------------------------------------------------------------------
extern "C" void kernel_launch(void* const* d_in, const int* in_sizes, int n_in,
                              void* d_out, int out_size, void* d_ws, size_t ws_size,
                              hipStream_t stream) {
    (void)in_sizes; (void)n_in; (void)out_size; (void)ws_size;
    const float* X       = (const float*)d_in[0];
    const int*   ei      = (const int*)d_in[1];
    const float* gat_w   = (const float*)d_in[2];
    const float* att_src = (const float*)d_in[3];
    const float* att_dst = (const float*)d_in[4];
    const float* gat_b   = (const float*)d_in[5];
    const float* w_ih0   = (const float*)d_in[6];
    const float* w_hh0   = (const float*)d_in[7];
    const float* b_ih0   = (const float*)d_in[8];
    const float* b_hh0   = (const float*)d_in[9];
    const float* w_ih1   = (const float*)d_in[10];
    const float* w_hh1   = (const float*)d_in[11];
    const float* b_ih1   = (const float*)d_in[12];
    const float* b_hh1   = (const float*)d_in[13];
    const float* fc_w    = (const float*)d_in[14];
    const float* fc_b    = (const float*)d_in[15];
    float* out = (float*)d_out;

    char* ws = (char*)d_ws;
    size_t off = 0;
    auto alloc_f = [&](size_t n) { float* p = (float*)(ws + off); off += n * sizeof(float); return p; };
    auto alloc_i = [&](size_t n) { int* p = (int*)(ws + off); off += n * sizeof(int); return p; };

    float*  gat_out = alloc_f((size_t)NT * HID);        // 4.6 MB
    float2* Xt      = (float2*)alloc_f((size_t)NT * 2); // 288 KB
    float*  proj    = alloc_f(32);
    int* deg       = alloc_i(N_NODES);
    int* row_start = alloc_i(N_NODES + 1);
    int* cursor    = alloc_i(N_NODES);
    int* csr_src   = alloc_i(E_TOT);

    k_init<<<13 + (NT + 255) / 256, 256, 0, stream>>>(deg, gat_w, att_src, att_dst,
                                                      proj, X, Xt);
    k_deg<<<(E_TOT + 255) / 256, 256, 0, stream>>>(ei, deg);
    k_scan<<<1, 256, 0, stream>>>(deg, row_start, cursor);
    k_scatter<<<(E_TOT + 255) / 256, 256, 0, stream>>>(ei, cursor, csr_src);
    k_gat<<<NT / 4, 256, 0, stream>>>(Xt, row_start, csr_src, proj,
                                      gat_w, gat_b, gat_out);
    k_lstm<<<N_NODES / 4, 256, 0, stream>>>(gat_out, w_ih0, w_hh0, b_ih0, b_hh0,
                                            w_ih1, w_hh1, b_ih1, b_hh1,
                                            fc_w, fc_b, out);
}